// Round 2
// baseline (2785.001 us; speedup 1.0000x reference)
//
#include <hip/hip_runtime.h>
#include <hip/hip_bf16.h>

// Problem constants
#define B_   64
#define N_   200
#define S_   201
#define E_   128
#define H_   8
#define D_   16
#define HD_  128
#define FF_  512
#define L_   6
#define TWOH_ 16

// ---------------- initial embedding ----------------
// x[b,0,:] = depot[b,0,:3] @ Wd + bd ; x[b,1+n,:] = node[b,n,:4] @ Wn + bn
__global__ void embed_kernel(const float* __restrict__ depot, const float* __restrict__ node,
                             const float* __restrict__ Wd, const float* __restrict__ bd,
                             const float* __restrict__ Wn, const float* __restrict__ bn,
                             float* __restrict__ X) {
  int idx = blockIdx.x * blockDim.x + threadIdx.x;
  if (idx >= B_ * S_ * E_) return;
  int e  = idx & (E_ - 1);
  int bs = idx >> 7;            // / E_
  int s  = bs % S_;
  int b  = bs / S_;
  float acc;
  if (s == 0) {
    acc = bd[e];
    #pragma unroll
    for (int i = 0; i < 3; ++i) acc += depot[b * 3 + i] * Wd[i * E_ + e];
  } else {
    acc = bn[e];
    const float* nd = node + ((size_t)b * N_ + (s - 1)) * 4;
    #pragma unroll
    for (int i = 0; i < 4; ++i) acc += nd[i] * Wn[i * E_ + e];
  }
  X[idx] = acc;
}

// ---------------- generic tiled GEMM ----------------
// C[M,N] = maybe_relu( (res? res[M,N]:0) + A[M,K] @ W[K,N] + (bias? bias[N]:0) )
// all f32. M%64==0, N%64==0, K%32==0.
__global__ __launch_bounds__(256) void gemm_kernel(
    const float* __restrict__ A, const float* __restrict__ W,
    const float* __restrict__ bias, const float* __restrict__ res,
    float* __restrict__ C, int M, int N, int K, int relu) {
  __shared__ float As[64][33];   // padded: avoid bank conflicts on As[r][kk]
  __shared__ float Ws[32][64];
  int tid = threadIdx.x;
  int m0 = blockIdx.x * 64;
  int n0 = blockIdx.y * 64;
  int tx = tid & 15, ty = tid >> 4;   // 16 x 16 thread grid, 4x4 microtile
  float acc[4][4] = {};
  for (int k0 = 0; k0 < K; k0 += 32) {
    {
      int p = tid * 8;
      int r = p >> 5, c = p & 31;                 // 64x32 tile, 8 contiguous per thread
      const float* src = A + (size_t)(m0 + r) * K + k0 + c;
      #pragma unroll
      for (int i = 0; i < 8; ++i) As[r][c + i] = src[i];
    }
    {
      int p = tid * 8;
      int r = p >> 6, c = p & 63;                 // 32x64 tile
      const float* src = W + (size_t)(k0 + r) * N + n0 + c;
      #pragma unroll
      for (int i = 0; i < 8; ++i) Ws[r][c + i] = src[i];
    }
    __syncthreads();
    #pragma unroll
    for (int kk = 0; kk < 32; ++kk) {
      float a[4], w[4];
      #pragma unroll
      for (int i = 0; i < 4; ++i) a[i] = As[ty * 4 + i][kk];
      #pragma unroll
      for (int j = 0; j < 4; ++j) w[j] = Ws[kk][tx * 4 + j];
      #pragma unroll
      for (int i = 0; i < 4; ++i)
        #pragma unroll
        for (int j = 0; j < 4; ++j) acc[i][j] += a[i] * w[j];
    }
    __syncthreads();
  }
  #pragma unroll
  for (int i = 0; i < 4; ++i) {
    int m = m0 + ty * 4 + i;
    #pragma unroll
    for (int j = 0; j < 4; ++j) {
      int n = n0 + tx * 4 + j;
      float v = acc[i][j];
      if (bias) v += bias[n];
      if (res)  v += res[(size_t)m * N + n];
      if (relu) v = v > 0.f ? v : 0.f;
      C[(size_t)m * N + n] = v;
    }
  }
}

// ---------------- attention scores: score[b,h,n,m] = sum_d q[b,n,h,d] k[b,m,h,d] ----------------
__global__ __launch_bounds__(256) void score_kernel(const float* __restrict__ Q,
                                                    const float* __restrict__ Kmat,
                                                    float* __restrict__ SC) {
  int bh = blockIdx.x;
  int h = bh % H_, b = bh / H_;
  __shared__ float qs[S_][D_ + 1];
  __shared__ float ks[S_][D_ + 1];
  int tid = threadIdx.x;
  for (int p = tid; p < S_ * D_; p += 256) {
    int r = p >> 4, d = p & 15;
    size_t g = ((size_t)(b * S_ + r)) * HD_ + h * D_ + d;
    qs[r][d] = Q[g];
    ks[r][d] = Kmat[g];
  }
  __syncthreads();
  float* out = SC + ((size_t)(b * H_ + h)) * S_ * S_;
  for (int p = tid; p < S_ * S_; p += 256) {
    int n = p / S_, m = p - n * S_;
    float acc = 0.f;
    #pragma unroll
    for (int d = 0; d < D_; ++d) acc += qs[n][d] * ks[m][d];
    out[(size_t)n * S_ + m] = acc;
  }
}

// ---------------- fused: per-(b,n) edge-MLP + softmax + PV ----------------
// cat[m][0:8] = score[b,:,n,m], cat[m][8:16] = route_attn[b,:,n,m]
// h1 = relu(cat @ A1w + A1b); agg[h] = h1 @ A2w + A2b
// w = softmax_m(agg); o[b,n,h,d] = sum_m w[h][m] * v[b,m,h,d]
__global__ __launch_bounds__(256) void attn_kernel(
    const float* __restrict__ SC, const float* __restrict__ RA,
    const float* __restrict__ A1w, const float* __restrict__ A1b,
    const float* __restrict__ A2w, const float* __restrict__ A2b,
    const float* __restrict__ V, float* __restrict__ O) {
  int bn = blockIdx.x;
  int n = bn % S_, b = bn / S_;
  __shared__ float cat[S_][TWOH_ + 1];
  __shared__ float P[H_][S_ + 3];
  __shared__ float w1[TWOH_][TWOH_];
  __shared__ float w2[TWOH_][H_];
  __shared__ float b1[TWOH_];
  __shared__ float b2[H_];
  __shared__ float sums[H_];
  int tid = threadIdx.x;
  if (tid < TWOH_ * TWOH_) w1[tid >> 4][tid & 15] = A1w[tid];
  if (tid < TWOH_ * H_)    w2[tid >> 3][tid & 7]  = A2w[tid];
  if (tid < TWOH_)         b1[tid] = A1b[tid];
  if (tid < H_)            b2[tid] = A2b[tid];
  // load cat: coalesced along m per head
  for (int p = tid; p < H_ * S_; p += 256) {
    int h = p / S_, m = p - h * S_;
    size_t g = (((size_t)b * H_ + h) * S_ + n) * S_ + m;
    cat[m][h]      = SC[g];
    cat[m][H_ + h] = RA[g];
  }
  __syncthreads();
  // edge MLP, one thread per m
  if (tid < S_) {
    int m = tid;
    float h1[TWOH_];
    #pragma unroll
    for (int j = 0; j < TWOH_; ++j) {
      float a = b1[j];
      #pragma unroll
      for (int i = 0; i < TWOH_; ++i) a += cat[m][i] * w1[i][j];
      h1[j] = a > 0.f ? a : 0.f;
    }
    #pragma unroll
    for (int h = 0; h < H_; ++h) {
      float a = b2[h];
      #pragma unroll
      for (int j = 0; j < TWOH_; ++j) a += h1[j] * w2[j][h];
      P[h][m] = a;
    }
  }
  __syncthreads();
  // softmax over m for each head: 8 groups of 32 lanes
  {
    int g = tid >> 5;      // head
    int lane = tid & 31;
    float mx = -1e30f;
    for (int m = lane; m < S_; m += 32) mx = fmaxf(mx, P[g][m]);
    #pragma unroll
    for (int off = 16; off > 0; off >>= 1) mx = fmaxf(mx, __shfl_xor(mx, off, 32));
    float sum = 0.f;
    for (int m = lane; m < S_; m += 32) {
      float e = __expf(P[g][m] - mx);
      P[g][m] = e;
      sum += e;
    }
    #pragma unroll
    for (int off = 16; off > 0; off >>= 1) sum += __shfl_xor(sum, off, 32);
    if (lane == 0) sums[g] = sum;
  }
  __syncthreads();
  // PV: thread (h,d)
  if (tid < H_ * D_) {
    int h = tid >> 4, d = tid & 15;
    float acc = 0.f;
    const float* vp = V + (size_t)b * S_ * HD_ + h * D_ + d;
    for (int m = 0; m < S_; ++m) acc += P[h][m] * vp[(size_t)m * HD_];
    O[((size_t)(b * S_ + n)) * HD_ + h * D_ + d] = acc / sums[h];
  }
}

// ---------------- instance norm over sequence axis ----------------
__global__ __launch_bounds__(512) void inorm_kernel(const float* __restrict__ Y,
                                                    const float* __restrict__ w,
                                                    const float* __restrict__ bb,
                                                    float* __restrict__ X) {
  int b = blockIdx.x;
  int tid = threadIdx.x;
  int e = tid & 127, sg = tid >> 7;   // 4 s-groups x 128 channels
  __shared__ float ps[4][128], pss[4][128];
  const float* base = Y + (size_t)b * S_ * E_;
  float s = 0.f, ss = 0.f;
  for (int i = sg; i < S_; i += 4) {
    float v = base[(size_t)i * E_ + e];
    s += v; ss += v * v;
  }
  ps[sg][e] = s; pss[sg][e] = ss;
  __syncthreads();
  if (sg == 0) {
    s  = ps[0][e] + ps[1][e] + ps[2][e] + ps[3][e];
    ss = pss[0][e] + pss[1][e] + pss[2][e] + pss[3][e];
    float mean = s / S_;
    float var  = fmaxf(ss / S_ - mean * mean, 0.f);
    float scale = rsqrtf(var + 1e-5f) * w[e];
    ps[0][e]  = scale;
    pss[0][e] = bb[e] - mean * scale;
  }
  __syncthreads();
  float scale = ps[0][e], shift = pss[0][e];
  float* dst = X + (size_t)b * S_ * E_;
  for (int i = sg; i < S_; i += 4) {
    size_t idx = (size_t)i * E_ + e;
    dst[idx] = base[idx] * scale + shift;
  }
}

extern "C" void kernel_launch(void* const* d_in, const int* in_sizes, int n_in,
                              void* d_out, int out_size, void* d_ws, size_t ws_size,
                              hipStream_t stream) {
  const float* depot = (const float*)d_in[0];
  const float* node  = (const float*)d_in[1];
  const float* RA    = (const float*)d_in[2];
  const float* Wd    = (const float*)d_in[3];
  const float* bd    = (const float*)d_in[4];
  const float* Wn    = (const float*)d_in[5];
  const float* bn    = (const float*)d_in[6];
  const float* Wq    = (const float*)d_in[7];
  const float* Wk    = (const float*)d_in[8];
  const float* Wv    = (const float*)d_in[9];
  const float* Wo    = (const float*)d_in[10];
  const float* bo    = (const float*)d_in[11];
  const float* A1w   = (const float*)d_in[12];
  const float* A1b   = (const float*)d_in[13];
  const float* A2w   = (const float*)d_in[14];
  const float* A2b   = (const float*)d_in[15];
  const float* n1w   = (const float*)d_in[16];
  const float* n1b   = (const float*)d_in[17];
  const float* n2w   = (const float*)d_in[18];
  const float* n2b   = (const float*)d_in[19];
  const float* F1w   = (const float*)d_in[20];
  const float* F1b   = (const float*)d_in[21];
  const float* F2w   = (const float*)d_in[22];
  const float* F2b   = (const float*)d_in[23];

  const size_t XSZ   = (size_t)B_ * S_ * E_;        // 1,646,592
  const size_t SCSZ  = (size_t)B_ * H_ * S_ * S_;   // 20,685,312
  float* ws = (float*)d_ws;
  float* X   = ws;            // [B,S,E]
  float* Q   = X  + XSZ;      // [B,S,H*D]
  float* Kb  = Q  + XSZ;
  float* V   = Kb + XSZ;
  float* O   = V  + XSZ;
  float* SC  = O  + XSZ;      // [B,H,S,S]
  float* TMP = SC;            // aliases SC (SC consumed before TMP written)
  float* HID = SC + XSZ;      // aliases SC (TMP+HID < SCSZ)
  // total ws use: (5*XSZ + SCSZ) * 4 = ~115.7 MB

  const int M = B_ * S_;  // 12864, divisible by 64

  auto gemm = [&](const float* A, const float* W, const float* bias,
                  const float* res, float* C, int Nn, int K, int relu) {
    dim3 grid(M / 64, Nn / 64);
    gemm_kernel<<<grid, 256, 0, stream>>>(A, W, bias, res, C, M, Nn, K, relu);
  };

  embed_kernel<<<(B_ * S_ * E_ + 255) / 256, 256, 0, stream>>>(depot, node, Wd, bd, Wn, bn, X);

  for (int l = 0; l < L_; ++l) {
    gemm(X, Wq + (size_t)l * E_ * HD_, nullptr, nullptr, Q,  HD_, E_, 0);
    gemm(X, Wk + (size_t)l * E_ * HD_, nullptr, nullptr, Kb, HD_, E_, 0);
    gemm(X, Wv + (size_t)l * E_ * HD_, nullptr, nullptr, V,  HD_, E_, 0);
    score_kernel<<<B_ * H_, 256, 0, stream>>>(Q, Kb, SC);
    attn_kernel<<<B_ * S_, 256, 0, stream>>>(SC, RA,
        A1w + (size_t)l * TWOH_ * TWOH_, A1b + (size_t)l * TWOH_,
        A2w + (size_t)l * TWOH_ * H_,    A2b + (size_t)l * H_, V, O);
    gemm(O, Wo + (size_t)l * HD_ * E_, bo + (size_t)l * E_, X, TMP, E_, HD_, 0);
    inorm_kernel<<<B_, 512, 0, stream>>>(TMP, n1w + (size_t)l * E_, n1b + (size_t)l * E_, X);
    gemm(X, F1w + (size_t)l * E_ * FF_, F1b + (size_t)l * FF_, nullptr, HID, FF_, E_, 1);
    gemm(HID, F2w + (size_t)l * FF_ * E_, F2b + (size_t)l * E_, X, TMP, E_, FF_, 0);
    // last layer: write the normalized result straight to d_out (f32)
    float* dst = (l == L_ - 1) ? (float*)d_out : X;
    inorm_kernel<<<B_, 512, 0, stream>>>(TMP, n2w + (size_t)l * E_, n2b + (size_t)l * E_, dst);
  }
}